// Round 1
// baseline (188.464 us; speedup 1.0000x reference)
//
#include <hip/hip_runtime.h>
#include <stdint.h>

#define NB 8
#define CC 64
#define OO 64
#define HH 128
#define WW 128
#define LL (HH*WW)        // 16384
#define NL (NB*LL)        // 131072

// workspace layout
#define WS_COUNTER_OFF 0
#define WS_WT_OFF      256
#define WS_WT_FLOATS   (27*4096)                 // [b][kk][c][o]
#define WS_LIST_OFF    (WS_WT_OFF + WS_WT_FLOATS*4)  // 442624

// ---------------------------------------------------------------------------
// Prep: zero the list counter; transpose weights to wT[b][kk][c][o] so that
// both the dense kernel (LDS broadcast) and sparse kernel (lane=o coalesced)
// read them efficiently.
// ---------------------------------------------------------------------------
__global__ __launch_bounds__(256) void prep_kernel(
    const float* __restrict__ w0, const float* __restrict__ w1,
    const float* __restrict__ w2, float* __restrict__ wT,
    unsigned int* __restrict__ counter)
{
    if (blockIdx.x == 0 && threadIdx.x == 0) *counter = 0u;
    int e = blockIdx.x * 256 + threadIdx.x;
    if (e < WS_WT_FLOATS) {
        int b  = e / 36864;            // 9*4096
        int r  = e - b * 36864;
        int kk = r >> 12;
        int q  = r & 4095;
        int c  = q >> 6;
        int o  = q & 63;
        const float* w = (b == 0) ? w0 : ((b == 1) ? w1 : w2);
        wT[e] = w[o * 576 + c * 9 + kk];   // (O,C,3,3) layout
    }
}

// ---------------------------------------------------------------------------
// Dense: per-pixel masks + sparse-list append + always-on center 1x1 conv.
// One thread per pixel; 64 fp32 accumulators; weights broadcast from LDS.
// ---------------------------------------------------------------------------
__global__ __launch_bounds__(256) void dense_kernel(
    const float* __restrict__ x, const float* __restrict__ depth,
    const float* __restrict__ fx, const float* __restrict__ wT,
    float* __restrict__ out, unsigned int* __restrict__ counter,
    unsigned int* __restrict__ list, int cap)
{
    __shared__ float lds_w[4096];                  // w1 center, [c][o]
    const float* wsrc = wT + 13 * 4096;            // b=1, kk=4
    for (int i = threadIdx.x; i < 4096; i += 256) lds_w[i] = wsrc[i];
    __syncthreads();

    int p = blockIdx.x * 256 + threadIdx.x;        // global pixel id, < NL
    int n = p >> 14;
    int l = p & (LL - 1);
    int h = l >> 7;
    int w = l & (WW - 1);

    const float* dptr = depth + (n << 14);
    float center = dptr[l];
    float fxv  = fx[n];
    float grid = center / fxv;                     // PIXEL_SIZE == 1.0
    float half_ = 0.5f * grid;
    float cpg = center + grid;
    float cmg = center - grid;

    // ---- masks + sparse list append (center/b1 handled densely) ----
    #pragma unroll
    for (int kh = 0; kh < 3; ++kh) {
        int hh = h + kh - 1;
        #pragma unroll
        for (int kw = 0; kw < 3; ++kw) {
            int ww = w + kw - 1;
            int kkid = kh * 3 + kw;
            if (hh < 0 || hh >= HH || ww < 0 || ww >= WW) continue;  // x_col==0 there
            float d = dptr[(hh << 7) + ww];
            bool m0 = fabsf(d - cpg)    <= half_;
            bool m1 = fabsf(d - center) <= half_;
            bool m2 = fabsf(d - cmg)    <= half_;
            if (kkid == 4) m1 = false;              // dense path covers it
            unsigned bits = (m0 ? 1u : 0u) | (m1 ? 2u : 0u) | (m2 ? 4u : 0u);
            while (bits) {
                int b = __ffs(bits) - 1;
                bits &= bits - 1;
                unsigned pos = atomicAdd(counter, 1u);
                if (pos < (unsigned)cap)
                    list[pos] = ((unsigned)p << 6) | ((unsigned)kkid << 2) | (unsigned)b;
            }
        }
    }

    // ---- dense 1x1 conv: out[n,:,l] = W1c @ x[n,:,l] ----
    float acc[64];
    #pragma unroll
    for (int o = 0; o < 64; ++o) acc[o] = 0.f;

    const float* xb = x + ((long)(n << 6) << 14) + l;
    #pragma unroll 4
    for (int c = 0; c < 64; ++c) {
        float xv = xb[(long)c << 14];
        const float4* wrow = (const float4*)&lds_w[c << 6];
        #pragma unroll
        for (int o4 = 0; o4 < 16; ++o4) {
            float4 wv = wrow[o4];      // wave-uniform LDS broadcast
            acc[4*o4+0] = fmaf(wv.x, xv, acc[4*o4+0]);
            acc[4*o4+1] = fmaf(wv.y, xv, acc[4*o4+1]);
            acc[4*o4+2] = fmaf(wv.z, xv, acc[4*o4+2]);
            acc[4*o4+3] = fmaf(wv.w, xv, acc[4*o4+3]);
        }
    }

    float* ob = out + ((long)(n << 6) << 14) + l;
    #pragma unroll
    for (int o = 0; o < 64; ++o) ob[(long)o << 14] = acc[o];
}

// ---------------------------------------------------------------------------
// Sparse: one wave per list item; lane = output channel o.
// out[n,:,l] += W_b[:,:,kk] @ x[n,:,l+offset(kk)]
// ---------------------------------------------------------------------------
__global__ __launch_bounds__(256) void sparse_kernel(
    const float* __restrict__ x, const float* __restrict__ wT,
    float* __restrict__ out,
    const unsigned int* __restrict__ counter,
    const unsigned int* __restrict__ list, int cap, int nwaves)
{
    int lane = threadIdx.x & 63;
    int wid  = blockIdx.x * (blockDim.x >> 6) + (threadIdx.x >> 6);
    unsigned cnt = *counter;
    if (cnt > (unsigned)cap) cnt = (unsigned)cap;

    for (unsigned i = wid; i < cnt; i += (unsigned)nwaves) {
        unsigned item = list[i];
        int b    = item & 3;
        int kkid = (item >> 2) & 15;
        unsigned p = item >> 6;
        int n = p >> 14;
        int l = p & (LL - 1);
        int dh = kkid / 3 - 1, dw = kkid % 3 - 1;
        int l2 = l + dh * WW + dw;                 // in-bounds by construction

        const float* wt = wT + ((b * 9 + kkid) << 12);   // [c][o]
        const float* xb = x + ((long)(n << 6) << 14) + l2;

        float acc = 0.f;
        #pragma unroll 8
        for (int c = 0; c < 64; ++c)
            acc = fmaf(wt[(c << 6) + lane], xb[(long)c << 14], acc);

        atomicAdd(&out[(((long)(n << 6) + lane) << 14) + l], acc);
    }
}

// ---------------------------------------------------------------------------
extern "C" void kernel_launch(void* const* d_in, const int* in_sizes, int n_in,
                              void* d_out, int out_size, void* d_ws, size_t ws_size,
                              hipStream_t stream)
{
    const float* x     = (const float*)d_in[0];
    const float* depth = (const float*)d_in[1];
    const float* fx    = (const float*)d_in[2];
    const float* w0    = (const float*)d_in[3];
    const float* w1    = (const float*)d_in[4];
    const float* w2    = (const float*)d_in[5];
    float* out = (float*)d_out;

    unsigned char* ws = (unsigned char*)d_ws;
    unsigned int* counter = (unsigned int*)(ws + WS_COUNTER_OFF);
    float*        wT      = (float*)(ws + WS_WT_OFF);
    unsigned int* lst     = (unsigned int*)(ws + WS_LIST_OFF);

    long long cap_ll = ((long long)ws_size - WS_LIST_OFF) / 4;
    if (cap_ll < 0) cap_ll = 0;
    if (cap_ll > (long long)NL * 27) cap_ll = (long long)NL * 27;
    int cap = (int)cap_ll;

    prep_kernel  <<<(WS_WT_FLOATS + 255) / 256, 256, 0, stream>>>(w0, w1, w2, wT, counter);
    dense_kernel <<<NL / 256, 256, 0, stream>>>(x, depth, fx, wT, out, counter, lst, cap);
    sparse_kernel<<<128, 256, 0, stream>>>(x, wT, out, counter, lst, cap, 128 * 4);
}

// Round 2
// 152.938 us; speedup vs baseline: 1.2323x; 1.2323x over previous
//
#include <hip/hip_runtime.h>
#include <stdint.h>

#define NB 8
#define CC 64
#define OO 64
#define HH 128
#define WW 128
#define LL (HH*WW)        // 16384
#define NL (NB*LL)        // 131072

// workspace layout
#define WS_COUNTER_OFF 0
#define WS_WT_OFF      256
#define WS_WT_FLOATS   (27*4096)                 // [b][kk][c][o]
#define WS_LIST_OFF    (WS_WT_OFF + WS_WT_FLOATS*4)  // 442624

// ---------------------------------------------------------------------------
// Prep: zero the list counter; transpose weights to wT[b][kk][c][o].
// ---------------------------------------------------------------------------
__global__ __launch_bounds__(256) void prep_kernel(
    const float* __restrict__ w0, const float* __restrict__ w1,
    const float* __restrict__ w2, float* __restrict__ wT,
    unsigned int* __restrict__ counter)
{
    if (blockIdx.x == 0 && threadIdx.x == 0) *counter = 0u;
    int e = blockIdx.x * 256 + threadIdx.x;
    if (e < WS_WT_FLOATS) {
        int b  = e / 36864;            // 9*4096
        int r  = e - b * 36864;
        int kk = r >> 12;
        int q  = r & 4095;
        int c  = q >> 6;
        int o  = q & 63;
        const float* w = (b == 0) ? w0 : ((b == 1) ? w1 : w2);
        wT[e] = w[o * 576 + c * 9 + kk];   // (O,C,3,3) layout
    }
}

// ---------------------------------------------------------------------------
// Dense: block = 256 threads = 4 waves. All 4 waves share the same 64 pixels
// (lane = pixel); wave w computes output channels [16w, 16w+16).
// Weight reads are wave-uniform -> scalar s_load pipe; x reads coalesced.
// Wave 0 additionally computes the depth masks and appends sparse items.
// ---------------------------------------------------------------------------
__global__ __launch_bounds__(256, 8) void dense_kernel(
    const float* __restrict__ x, const float* __restrict__ depth,
    const float* __restrict__ fx, const float* __restrict__ wT,
    float* __restrict__ out, unsigned int* __restrict__ counter,
    unsigned int* __restrict__ list, int cap)
{
    const int lane = threadIdx.x & 63;
    const int wid  = __builtin_amdgcn_readfirstlane(threadIdx.x >> 6);  // 0..3

    const int p = blockIdx.x * 64 + lane;          // global pixel id, < NL
    const int n = p >> 14;
    const int l = p & (LL - 1);

    // ---- masks + sparse list append (wave 0 only; center/b1 done densely) ----
    if (wid == 0) {
        const int h = l >> 7;
        const int w = l & (WW - 1);
        const float* dptr = depth + (n << 14);
        float center = dptr[l];
        float grid = center / fx[n];               // PIXEL_SIZE == 1.0
        float half_ = 0.5f * grid;
        float cpg = center + grid;
        float cmg = center - grid;

        #pragma unroll
        for (int kh = 0; kh < 3; ++kh) {
            int hh = h + kh - 1;
            #pragma unroll
            for (int kw = 0; kw < 3; ++kw) {
                int ww = w + kw - 1;
                int kkid = kh * 3 + kw;
                if (hh < 0 || hh >= HH || ww < 0 || ww >= WW) continue;
                float d = dptr[(hh << 7) + ww];
                bool m0 = fabsf(d - cpg)    <= half_;
                bool m1 = fabsf(d - center) <= half_;
                bool m2 = fabsf(d - cmg)    <= half_;
                if (kkid == 4) m1 = false;          // dense path covers it
                unsigned bits = (m0 ? 1u : 0u) | (m1 ? 2u : 0u) | (m2 ? 4u : 0u);
                while (bits) {
                    int b = __ffs(bits) - 1;
                    bits &= bits - 1;
                    unsigned pos = atomicAdd(counter, 1u);
                    if (pos < (unsigned)cap)
                        list[pos] = ((unsigned)p << 6) | ((unsigned)kkid << 2) | (unsigned)b;
                }
            }
        }
    }

    // ---- dense 1x1 conv: acc[o16] = sum_c w1c[c][o] * x[n,c,l] ----
    float acc[16];
    #pragma unroll
    for (int i = 0; i < 16; ++i) acc[i] = 0.f;

    const float* __restrict__ xb = x + (((long)n << 6) << 14) + l;
    const float* __restrict__ wc = wT + 13 * 4096 + (wid << 4);   // [c][o] slice

    #pragma unroll 4
    for (int c = 0; c < 64; ++c) {
        float xv = xb[(long)c << 14];
        const float* wr = wc + (c << 6);           // wave-uniform address
        #pragma unroll
        for (int i = 0; i < 16; ++i)
            acc[i] = fmaf(wr[i], xv, acc[i]);
    }

    float* ob = out + (((long)n << 6) << 14) + ((long)(wid << 4) << 14) + l;
    #pragma unroll
    for (int i = 0; i < 16; ++i)
        ob[(long)i << 14] = acc[i];
}

// ---------------------------------------------------------------------------
// Sparse: one wave per list item; lane = output channel o.
// out[n,:,l] += W_b[:,:,kk] @ x[n,:,l+offset(kk)]
// ---------------------------------------------------------------------------
__global__ __launch_bounds__(256) void sparse_kernel(
    const float* __restrict__ x, const float* __restrict__ wT,
    float* __restrict__ out,
    const unsigned int* __restrict__ counter,
    const unsigned int* __restrict__ list, int cap, int nwaves)
{
    int lane = threadIdx.x & 63;
    int wid  = blockIdx.x * (blockDim.x >> 6) + (threadIdx.x >> 6);
    unsigned cnt = *counter;
    if (cnt > (unsigned)cap) cnt = (unsigned)cap;

    for (unsigned i = wid; i < cnt; i += (unsigned)nwaves) {
        unsigned item = list[i];
        int b    = item & 3;
        int kkid = (item >> 2) & 15;
        unsigned p = item >> 6;
        int n = p >> 14;
        int l = p & (LL - 1);
        int dh = kkid / 3 - 1, dw = kkid % 3 - 1;
        int l2 = l + dh * WW + dw;                 // in-bounds by construction

        const float* wt = wT + ((b * 9 + kkid) << 12);   // [c][o]
        const float* xb = x + (((long)n << 6) << 14) + l2;

        float acc = 0.f;
        #pragma unroll 8
        for (int c = 0; c < 64; ++c)
            acc = fmaf(wt[(c << 6) + lane], xb[(long)c << 14], acc);

        atomicAdd(&out[((((long)n << 6) + lane) << 14) + l], acc);
    }
}

// ---------------------------------------------------------------------------
extern "C" void kernel_launch(void* const* d_in, const int* in_sizes, int n_in,
                              void* d_out, int out_size, void* d_ws, size_t ws_size,
                              hipStream_t stream)
{
    const float* x     = (const float*)d_in[0];
    const float* depth = (const float*)d_in[1];
    const float* fx    = (const float*)d_in[2];
    const float* w0    = (const float*)d_in[3];
    const float* w1    = (const float*)d_in[4];
    const float* w2    = (const float*)d_in[5];
    float* out = (float*)d_out;

    unsigned char* ws = (unsigned char*)d_ws;
    unsigned int* counter = (unsigned int*)(ws + WS_COUNTER_OFF);
    float*        wT      = (float*)(ws + WS_WT_OFF);
    unsigned int* lst     = (unsigned int*)(ws + WS_LIST_OFF);

    long long cap_ll = ((long long)ws_size - WS_LIST_OFF) / 4;
    if (cap_ll < 0) cap_ll = 0;
    if (cap_ll > (long long)NL * 27) cap_ll = (long long)NL * 27;
    int cap = (int)cap_ll;

    prep_kernel  <<<(WS_WT_FLOATS + 255) / 256, 256, 0, stream>>>(w0, w1, w2, wT, counter);
    dense_kernel <<<NL / 64, 256, 0, stream>>>(x, depth, fx, wT, out, counter, lst, cap);
    sparse_kernel<<<256, 256, 0, stream>>>(x, wT, out, counter, lst, cap, 256 * 4);
}

// Round 3
// 149.705 us; speedup vs baseline: 1.2589x; 1.0216x over previous
//
#include <hip/hip_runtime.h>
#include <stdint.h>

#define NB 8
#define CC 64
#define OO 64
#define HH 128
#define WW 128
#define LL (HH*WW)        // 16384
#define NL (NB*LL)        // 131072

// workspace layout
#define WS_COUNTER_OFF 0
#define WS_WT_OFF      256
#define WS_WT_FLOATS   (27*4096)                 // [b][kk][c][o]
#define WS_LIST_OFF    (WS_WT_OFF + WS_WT_FLOATS*4)  // 442624

// ---------------------------------------------------------------------------
// Prep: zero the list counter; transpose weights to wT[b][kk][c][o].
// ---------------------------------------------------------------------------
__global__ __launch_bounds__(256) void prep_kernel(
    const float* __restrict__ w0, const float* __restrict__ w1,
    const float* __restrict__ w2, float* __restrict__ wT,
    unsigned int* __restrict__ counter)
{
    if (blockIdx.x == 0 && threadIdx.x == 0) *counter = 0u;
    int e = blockIdx.x * 256 + threadIdx.x;
    if (e < WS_WT_FLOATS) {
        int b  = e / 36864;            // 9*4096
        int r  = e - b * 36864;
        int kk = r >> 12;
        int q  = r & 4095;
        int c  = q >> 6;
        int o  = q & 63;
        const float* w = (b == 0) ? w0 : ((b == 1) ? w1 : w2);
        wT[e] = w[o * 576 + c * 9 + kk];   // (O,C,3,3) layout
    }
}

// ---------------------------------------------------------------------------
// Dense: block = 512 threads = 8 waves; block covers 256 consecutive pixels.
// Each thread: 4 pixels (float4 x loads), 8 output channels (wave-sliced).
// Weights wave-uniform -> scalar pipe. Waves 0..3 also compute masks (1 px
// per lane) and append sparse-correction items.
// ---------------------------------------------------------------------------
__global__ __launch_bounds__(512, 4) void dense_kernel(
    const float* __restrict__ x, const float* __restrict__ depth,
    const float* __restrict__ fx, const float* __restrict__ wT,
    float* __restrict__ out, unsigned int* __restrict__ counter,
    unsigned int* __restrict__ list, int cap)
{
    const int lane = threadIdx.x & 63;
    const int wid  = __builtin_amdgcn_readfirstlane(threadIdx.x >> 6);  // 0..7

    const int pbase = blockIdx.x << 8;           // 256 px per block, same image
    const int n     = pbase >> 14;
    const int lbase = pbase & (LL - 1);

    // ---- masks + sparse list append (waves 0..3; center/b1 done densely) ----
    if (wid < 4) {
        const int l = lbase + (wid << 6) + lane;
        const int p = pbase + (wid << 6) + lane;
        const int h = l >> 7;
        const int w = l & (WW - 1);
        const float* dptr = depth + (n << 14);
        float center = dptr[l];
        float grid = center / fx[n];             // PIXEL_SIZE == 1.0
        float half_ = 0.5f * grid;
        float cpg = center + grid;
        float cmg = center - grid;

        #pragma unroll
        for (int kh = 0; kh < 3; ++kh) {
            int hh = h + kh - 1;
            #pragma unroll
            for (int kw = 0; kw < 3; ++kw) {
                int ww = w + kw - 1;
                int kkid = kh * 3 + kw;
                if (hh < 0 || hh >= HH || ww < 0 || ww >= WW) continue;
                float d = dptr[(hh << 7) + ww];
                bool m0 = fabsf(d - cpg)    <= half_;
                bool m1 = fabsf(d - center) <= half_;
                bool m2 = fabsf(d - cmg)    <= half_;
                if (kkid == 4) m1 = false;        // dense path covers it
                unsigned bits = (m0 ? 1u : 0u) | (m1 ? 2u : 0u) | (m2 ? 4u : 0u);
                while (bits) {
                    int b = __ffs(bits) - 1;
                    bits &= bits - 1;
                    unsigned pos = atomicAdd(counter, 1u);
                    if (pos < (unsigned)cap)
                        list[pos] = ((unsigned)p << 6) | ((unsigned)kkid << 2) | (unsigned)b;
                }
            }
        }
    }

    // ---- dense 1x1 conv: acc[o8][px4] = sum_c w1c[c][o] * x[n,c,l0..l0+3] ----
    const int l0 = lbase + (lane << 2);
    const float4* __restrict__ xb = (const float4*)(x + ((long)n << 20) + l0);
    const float* __restrict__ wc = wT + 13 * 4096 + (wid << 3);

    float4 acc[8];
    #pragma unroll
    for (int o = 0; o < 8; ++o) acc[o] = make_float4(0.f, 0.f, 0.f, 0.f);

    #pragma unroll 8
    for (int c = 0; c < 64; ++c) {
        float4 xv = xb[c << 12];                 // 16 B/lane, coalesced 1 KiB/wave
        #pragma unroll
        for (int o = 0; o < 8; ++o) {
            float wv = wc[(c << 6) + o];         // wave-uniform -> s_load
            acc[o].x = fmaf(wv, xv.x, acc[o].x);
            acc[o].y = fmaf(wv, xv.y, acc[o].y);
            acc[o].z = fmaf(wv, xv.z, acc[o].z);
            acc[o].w = fmaf(wv, xv.w, acc[o].w);
        }
    }

    float* ob = out + ((long)n << 20) + (((long)(wid << 3)) << 14) + l0;
    #pragma unroll
    for (int o = 0; o < 8; ++o)
        *(float4*)(ob + ((long)o << 14)) = acc[o];
}

// ---------------------------------------------------------------------------
// Sparse: one wave per list item. lane=c gathers x[n,:,l2] in ONE load
// instruction -> LDS (double-buffered); lane=o then consumes via LDS
// broadcast with coalesced L2-hot weight loads.
// out[n,:,l] += W_b[:,:,kk] @ x[n,:,l2]
// ---------------------------------------------------------------------------
#define SP_BLOCKS 512
__global__ __launch_bounds__(256) void sparse_kernel(
    const float* __restrict__ x, const float* __restrict__ wT,
    float* __restrict__ out,
    const unsigned int* __restrict__ counter,
    const unsigned int* __restrict__ list, int cap)
{
    __shared__ float xs[4][2][64];
    const int lane  = threadIdx.x & 63;
    const int wslot = threadIdx.x >> 6;
    const int wid   = blockIdx.x * 4 + wslot;
    const int nwaves = SP_BLOCKS * 4;

    unsigned cnt = *counter;
    if (cnt > (unsigned)cap) cnt = (unsigned)cap;

    int buf = 0;
    for (unsigned i = (unsigned)wid; i < cnt; i += (unsigned)nwaves, buf ^= 1) {
        unsigned item = list[i];
        int b    = item & 3;
        int kkid = (item >> 2) & 15;
        unsigned p = item >> 6;
        int n = (int)(p >> 14);
        int l = (int)(p & (LL - 1));
        int dh = kkid / 3 - 1, dw = kkid % 3 - 1;
        int l2 = l + dh * WW + dw;               // in-bounds by construction

        // one-instruction gather of the 64-channel input vector
        xs[wslot][buf][lane] = x[((long)n << 20) + ((long)lane << 14) + l2];

        const float* wt = wT + ((b * 9 + kkid) << 12);   // [c][o]
        const float* xv = xs[wslot][buf];

        float acc = 0.f;
        #pragma unroll 8
        for (int c = 0; c < 64; ++c)
            acc = fmaf(wt[(c << 6) + lane], xv[c], acc);

        atomicAdd(&out[((long)n << 20) + ((long)lane << 14) + l], acc);
    }
}

// ---------------------------------------------------------------------------
extern "C" void kernel_launch(void* const* d_in, const int* in_sizes, int n_in,
                              void* d_out, int out_size, void* d_ws, size_t ws_size,
                              hipStream_t stream)
{
    const float* x     = (const float*)d_in[0];
    const float* depth = (const float*)d_in[1];
    const float* fx    = (const float*)d_in[2];
    const float* w0    = (const float*)d_in[3];
    const float* w1    = (const float*)d_in[4];
    const float* w2    = (const float*)d_in[5];
    float* out = (float*)d_out;

    unsigned char* ws = (unsigned char*)d_ws;
    unsigned int* counter = (unsigned int*)(ws + WS_COUNTER_OFF);
    float*        wT      = (float*)(ws + WS_WT_OFF);
    unsigned int* lst     = (unsigned int*)(ws + WS_LIST_OFF);

    long long cap_ll = ((long long)ws_size - WS_LIST_OFF) / 4;
    if (cap_ll < 0) cap_ll = 0;
    if (cap_ll > (long long)NL * 27) cap_ll = (long long)NL * 27;
    int cap = (int)cap_ll;

    prep_kernel  <<<(WS_WT_FLOATS + 255) / 256, 256, 0, stream>>>(w0, w1, w2, wT, counter);
    dense_kernel <<<NL / 256, 512, 0, stream>>>(x, depth, fx, wT, out, counter, lst, cap);
    sparse_kernel<<<SP_BLOCKS, 256, 0, stream>>>(x, wT, out, counter, lst, cap);
}